// Round 10
// baseline (278.852 us; speedup 1.0000x reference)
//
#include <hip/hip_runtime.h>

// BoTNet attention, MI355X bf16-MFMA, round 15 (resubmit; R9 bench was an
// infra failure - GPU acquisition timeout - kernel never ran).
//  * raw .view: (b,o,s) row-major == (bh,i,d) row-major -> no relayout.
//  * pos bias folded into K; log2(e) folded into Q scale (exp2 softmax).
//  * S^T trick + pi-permuted K staging: softmaxed accumulators packed to bf16
//    ARE the PV A-fragments. pi: pr = (r&0x23)|((r&0x0C)<<1)|((r&0x10)>>2).
//  * R9: BK=128/buffer, ones-B MFMA row sums, setprio. flash 78->69us.
//  * R12: in-block KV-split (512 thr), in-LDS combine, f32 out. 170.7us.
//  * R14 (REVERTED): ds_read_b64_tr_b16 path failed correctness (absmax
//    0.33) -- HW lane-gather semantics not as modeled. Reverted.
//  * R15: v_transpose DELETED via register transpose in flash. V loaded
//    natural-layout (coalesced dwordx4 -> VGPR, T14 issue-early/write-late),
//    then scattered to LDS with the EXACT image R12's staging produced
//    (row=d, col-group (j>>3)^(d&7), col j&7) -> compute_tile and all MFMA
//    algebra are bit-identical to the proven R12 path. Saves the 67 MB
//    HBM round-trip + one launch; costs 32 ds_write_b16/thread/fill (~2%).
// ws: Q | K' | V (8 MiB each) | Wb16.

typedef float  f32x4  __attribute__((ext_vector_type(4)));
typedef __bf16 bf16x8 __attribute__((ext_vector_type(8)));
typedef __bf16 bf16x4 __attribute__((ext_vector_type(4)));

__device__ inline float fast_exp2(float x) {
#if __has_builtin(__builtin_amdgcn_exp2f)
  return __builtin_amdgcn_exp2f(x);
#else
  return exp2f(x);
#endif
}

__device__ inline void glds16(const __bf16* g, __bf16* l) {
  __builtin_amdgcn_global_load_lds(
      (const __attribute__((address_space(1))) void*)g,
      (__attribute__((address_space(3))) void*)l, 16, 0, 0);
}

// ---------------------------------------------------------------------------
// Kernel 0: W f32 -> bf16.
// ---------------------------------------------------------------------------
__global__ __launch_bounds__(256) void w_cvt(
    const float* __restrict__ w, __bf16* __restrict__ wb)
{
  int idx = blockIdx.x * 256 + threadIdx.x;
  f32x4 v = ((const f32x4*)w)[idx];
  bf16x4 o; o[0]=(__bf16)v[0]; o[1]=(__bf16)v[1]; o[2]=(__bf16)v[2]; o[3]=(__bf16)v[3];
  ((bf16x4*)wb)[idx] = o;
}

// ---------------------------------------------------------------------------
// Kernel 1: qkv projection (R12 version, bf16 W).
// ---------------------------------------------------------------------------
__global__ __launch_bounds__(256) void qkv_proj(
    const float* __restrict__ fmap, const __bf16* __restrict__ wb,
    const float* __restrict__ ph,   const float* __restrict__ pw,
    __bf16* __restrict__ Qw, __bf16* __restrict__ Kw, __bf16* __restrict__ Vw)
{
  constexpr int LS = 264;
  __shared__ __bf16 Bs[32 * LS];
  const int tid  = threadIdx.x;
  const int wv   = tid >> 6;
  const int lane = tid & 63;
  const int quad = lane >> 4, l15 = lane & 15;
  const int n0 = blockIdx.x * 32;
  const int b  = blockIdx.y;

#pragma unroll
  for (int i = 0; i < 2; ++i) {
    int id = tid + i * 256;
    int ng = id & 7;
    int kg = id >> 3;
    const float* base = fmap + ((size_t)b * 256 + 4 * kg) * 4096 + n0 + 4 * ng;
    f32x4 v0 = *(const f32x4*)(base);
    f32x4 v1 = *(const f32x4*)(base + 4096);
    f32x4 v2 = *(const f32x4*)(base + 8192);
    f32x4 v3 = *(const f32x4*)(base + 12288);
#pragma unroll
    for (int j = 0; j < 4; ++j) {
      bf16x4 o; o[0]=(__bf16)v0[j]; o[1]=(__bf16)v1[j]; o[2]=(__bf16)v2[j]; o[3]=(__bf16)v3[j];
      *(bf16x4*)(&Bs[(4 * ng + j) * LS + 4 * kg]) = o;
    }
  }
  __syncthreads();

  for (int mt = 0; mt < 12; ++mt) {
    const int region = mt >> 2;
    const int obase  = (mt & 3) * 64;
    const __bf16* aptr = wb + (size_t)(mt * 64 + 16 * wv + l15) * 256 + 8 * quad;

    f32x4 acc[2] = {};
#pragma unroll
    for (int k0 = 0; k0 < 256; k0 += 32) {
      bf16x8 af = *(const bf16x8*)(aptr + k0);
      bf16x8 b0 = *(const bf16x8*)(&Bs[(l15)      * LS + k0 + 8 * quad]);
      bf16x8 b1 = *(const bf16x8*)(&Bs[(16 + l15) * LS + k0 + 8 * quad]);
      acc[0] = __builtin_amdgcn_mfma_f32_16x16x32_bf16(af, b0, acc[0], 0, 0, 0);
      acc[1] = __builtin_amdgcn_mfma_f32_16x16x32_bf16(af, b1, acc[1], 0, 0, 0);
    }

#pragma unroll
    for (int t = 0; t < 2; ++t) {
#pragma unroll
      for (int rr = 0; rr < 4; ++rr) {
        int oreg = obase + 16 * wv + 4 * quad + rr;
        int s    = n0 + 16 * t + l15;
        float val = acc[t][rr];
        size_t off = ((size_t)(b * 256 + oreg)) * 4096 + s;
        if (region == 0) {
          Qw[off] = (__bf16)(val * 0.18033688f);      // 0.125 * log2(e)
        } else if (region == 1) {
          int g = oreg & 63;
          float bias = ph[g * 64 + (s & 63)] + pw[(s >> 6) * 64 + (s & 63)];
          Kw[off] = (__bf16)(val + bias);
        } else {
          Vw[off] = (__bf16)val;
        }
      }
    }
  }
}

// ---------------------------------------------------------------------------
// Kernel 2: flash attention v15. 512 threads = 8 waves; waves 0-3 kv
// [0,2048), waves 4-7 kv [2048,4096), same 256 Q rows. m=4/wave, BK=128 per
// LDS buffer, 2-stage DMA pipeline (K via glds16; V via reg-transpose
// staging, issue-early/write-late), in-LDS partial combine, direct f32 out.
// grid (16,16), block 512.
// ---------------------------------------------------------------------------
__global__ __launch_bounds__(512, 2) void flash_attn(
    const __bf16* __restrict__ Qg, const __bf16* __restrict__ Kg,
    const __bf16* __restrict__ Vg, float* __restrict__ out)
{
  // 128 KiB: K tiles [z][buf][4096] then V tiles [z][buf][4096].
  __shared__ __align__(16) __bf16 SMEM[65536];
  __bf16* Ks = SMEM;                      // 32768 elems (64 KiB)
  __bf16* Vs = SMEM + 32768;              // 32768 elems (64 KiB)

  const int tid  = threadIdx.x;
  const int wv   = tid >> 6;
  const int lane = tid & 63;
  const int quad = lane >> 4, l15 = lane & 15;
  const int zi   = wv >> 2;               // kv half this wave computes
  const int wl   = wv & 3;                // q-slot within the half
  const int bh = blockIdx.y;
  const int iw = blockIdx.x * 256 + 64 * wl;
  const __bf16* Qb = Qg + (size_t)bh * 262144;
  const __bf16* Kb = Kg + (size_t)bh * 262144;
  const __bf16* Vb = Vg + (size_t)bh * 262144;   // natural (j, d) layout

  // Q B-frags in registers
  bf16x8 qf[4][2];
#pragma unroll
  for (int m = 0; m < 4; ++m)
#pragma unroll
    for (int c = 0; c < 2; ++c)
      qf[m][c] = *(const bf16x8*)(Qb + (size_t)(iw + 16 * m + l15) * 64 + 32 * c + 8 * quad);

  // K staging (pi rows + source-side xor swizzle -- R12 path, proven).
  const int r0  = tid >> 3;
  const int kch = tid & 7;
  const int xc  = (kch ^ (r0 & 7)) * 8;
  const int prr = (r0 & 0x23) | ((r0 & 0x0C) << 1) | ((r0 & 0x10) >> 2);
  const __bf16* kp0 = Kb + (size_t)prr * 64 + xc;             // kv half 0
  const __bf16* kp1 = Kb + (size_t)(2048 + prr) * 64 + xc;    // kv half 1

  // V reg-transpose staging coords: lane holds V[jv][d0v .. d0v+8).
  const int jv  = tid >> 3;               // j within 64-row sub-tile
  const int d0v = (tid & 7) * 8;          // d base (multiple of 8)

  f32x4 acco[4][4] = {};
  f32x4 lacc[4] = {};                     // row sums via ones-B MFMA
  const int swz = (l15 & 7);

  bf16x8 onesb;
#pragma unroll
  for (int r = 0; r < 8; ++r) onesb[r] = (__bf16)1.0f;

  // --- K DMA: per buffer, 4 glds16/thread fill K for both halves. ---
  auto dma_k = [&](int buf) {
    __bf16* kd0 = &Ks[buf * 8192 + tid * 8];            // z=0
    __bf16* kd1 = &Ks[16384 + buf * 8192 + tid * 8];    // z=1
    glds16(kp0, kd0);         kp0 += 4096;   // sub0 (+64 K rows)
    glds16(kp0, kd0 + 4096);  kp0 += 4096;   // sub1
    glds16(kp1, kd1);         kp1 += 4096;
    glds16(kp1, kd1 + 4096);  kp1 += 4096;
  };

  // --- V loads: natural rows, coalesced (tj = tile j-base within half). ---
  auto v_loads = [&](int tj, bf16x8* vr) {
#pragma unroll
    for (int i = 0; i < 4; ++i) {
      int zl = i >> 1, sub = i & 1;
      vr[i] = *(const bf16x8*)(Vb + (size_t)(zl * 2048 + tj + sub * 64 + jv) * 64 + d0v);
    }
  };

  // --- V writes: scatter to R12's exact LDS image:
  //     elem = d*64 + ((j>>3)^(d&7))*8 + (j&7), rows = d. ---
  auto v_writes = [&](int buf, const bf16x8* vr) {
    const int jlow = jv & 7;
    const int jgrp = jv >> 3;
#pragma unroll
    for (int i = 0; i < 4; ++i) {
      int zl = i >> 1, sub = i & 1;
      __bf16* base = &Vs[zl * 16384 + buf * 8192 + sub * 4096];
#pragma unroll
      for (int k = 0; k < 8; ++k) {
        int d = d0v + k;                  // d&7 == k
        base[d * 64 + ((jgrp ^ k) * 8) + jlow] = vr[i][k];
      }
    }
  };

  auto compute_tile = [&](int buf, int sub) {
    const __bf16* Kbuf = &Ks[zi * 16384 + buf * 8192 + sub * 4096];
    const __bf16* Vbuf = &Vs[zi * 16384 + buf * 8192 + sub * 4096];
    // S^T = mfma(K-slot rows, Q rows)
    f32x4 sacc[4][4] = {};
    __builtin_amdgcn_s_setprio(1);
#pragma unroll
    for (int c = 0; c < 2; ++c) {
#pragma unroll
      for (int t = 0; t < 4; ++t) {
        bf16x8 ak = *(const bf16x8*)(&Kbuf[(16 * t + l15) * 64 + (((4 * c + quad) ^ swz) * 8)]);
#pragma unroll
        for (int m = 0; m < 4; ++m)
          sacc[m][t] = __builtin_amdgcn_mfma_f32_16x16x32_bf16(ak, qf[m][c], sacc[m][t], 0, 0, 0);
      }
    }
    __builtin_amdgcn_s_setprio(0);
    // softmax numerator + pack PV A-frags (identity via pi)
    bf16x8 pf[4][2];
#pragma unroll
    for (int m = 0; m < 4; ++m) {
#pragma unroll
      for (int t = 0; t < 4; ++t)
#pragma unroll
        for (int r = 0; r < 4; ++r)
          sacc[m][t][r] = fast_exp2(sacc[m][t][r]);
#pragma unroll
      for (int c2 = 0; c2 < 2; ++c2) {
        bf16x8 a;
#pragma unroll
        for (int r = 0; r < 4; ++r) {
          a[r]     = (__bf16)sacc[m][2 * c2][r];
          a[4 + r] = (__bf16)sacc[m][2 * c2 + 1][r];
        }
        pf[m][c2] = a;
      }
    }
    // O += P . V ; l += P . 1 (ones-B MFMA row sums, all 16 cols identical)
    __builtin_amdgcn_s_setprio(1);
#pragma unroll
    for (int c2 = 0; c2 < 2; ++c2) {
#pragma unroll
      for (int t = 0; t < 4; ++t) {
        bf16x8 bv = *(const bf16x8*)(&Vbuf[(16 * t + l15) * 64 + (((4 * c2 + quad) ^ swz) * 8)]);
#pragma unroll
        for (int m = 0; m < 4; ++m)
          acco[m][t] = __builtin_amdgcn_mfma_f32_16x16x32_bf16(pf[m][c2], bv, acco[m][t], 0, 0, 0);
      }
#pragma unroll
      for (int m = 0; m < 4; ++m)
        lacc[m] = __builtin_amdgcn_mfma_f32_16x16x32_bf16(pf[m][c2], onesb, lacc[m], 0, 0, 0);
    }
    __builtin_amdgcn_s_setprio(0);
  };

  // --- 2-stage pipeline: 1 barrier per 128-row buffer (2 sub-tiles).
  // K glds16 issued at dma points (drained by the barrier's vmcnt(0));
  // V reg-loads issued at dma points, LDS-scattered after the compute pair
  // (T14 issue-early/write-late: HBM latency hides under ~2 tiles of MFMA).
  bf16x8 vreg[4];
  int tj = 0;
  dma_k(0);
  v_loads(tj, vreg); tj += 128;
  v_writes(0, vreg);                      // prologue: serial fill of buf0
  for (int it = 0; it < 16; it += 2) {
    __syncthreads();                      // buf0 resident; buf1 reads done
    dma_k(1);
    v_loads(tj, vreg); tj += 128;
    compute_tile(0, 0);
    compute_tile(0, 1);
    v_writes(1, vreg);                    // vmcnt wait via data-dep
    __syncthreads();                      // buf1 resident; buf0 reads done
    if (it < 14) {
      dma_k(0);
      v_loads(tj, vreg); tj += 128;
    }
    compute_tile(1, 0);
    compute_tile(1, 1);
    if (it < 14) v_writes(0, vreg);
  }

  // --- epilogue: in-LDS partial combine, normalized f32 out. ---
  __syncthreads();                        // K/V tiles dead; reuse as f32 X
  float* X = (float*)SMEM;                // 256 slots x 84 f32 (86 KiB)
  const int slot = (wl * 64 + lane) * 84;
  if (zi == 1) {
#pragma unroll
    for (int m = 0; m < 4; ++m) {
#pragma unroll
      for (int t = 0; t < 4; ++t)
        *(f32x4*)(&X[slot + m * 16 + t * 4]) = acco[m][t];
      *(f32x4*)(&X[slot + 64 + m * 4]) = lacc[m];
    }
  }
  __syncthreads();
  if (zi == 0) {
    float* Ob = out + (size_t)bh * 262144;
#pragma unroll
    for (int m = 0; m < 4; ++m) {
      f32x4 l1 = *(const f32x4*)(&X[slot + 64 + m * 4]);
      f32x4 lt = lacc[m] + l1;
      f32x4 inv;
#pragma unroll
      for (int r = 0; r < 4; ++r) inv[r] = 1.0f / lt[r];
#pragma unroll
      for (int t = 0; t < 4; ++t) {
        f32x4 o1 = *(const f32x4*)(&X[slot + m * 16 + t * 4]);
        f32x4 ot = acco[m][t] + o1;
#pragma unroll
        for (int r = 0; r < 4; ++r)
          Ob[(size_t)(iw + 16 * m + 4 * quad + r) * 64 + 16 * t + l15] =
              ot[r] * inv[r];
      }
    }
  }
}

// ---------------------------------------------------------------------------
extern "C" void kernel_launch(void* const* d_in, const int* in_sizes, int n_in,
                              void* d_out, int out_size, void* d_ws, size_t ws_size,
                              hipStream_t stream) {
  const float* fmap = (const float*)d_in[0];
  const float* w    = (const float*)d_in[1];
  const float* ph   = (const float*)d_in[2];
  const float* pw   = (const float*)d_in[3];
  float* out = (float*)d_out;

  __bf16* Qw = (__bf16*)d_ws;            // 4*256*4096 elems each (8 MiB)
  __bf16* Kw = Qw + 4194304;
  __bf16* Vw = Kw + 4194304;
  __bf16* Wb16 = Vw + 4194304;           // 768*256 bf16 (384 KiB)

  w_cvt    <<<dim3(192),    256, 0, stream>>>(w, Wb16);
  qkv_proj <<<dim3(128, 4), 256, 0, stream>>>(fmap, Wb16, ph, pw, Qw, Kw, Vw);
  flash_attn<<<dim3(16, 16), 512, 0, stream>>>(Qw, Kw, Vw, out);
}

// Round 11
// 173.312 us; speedup vs baseline: 1.6090x; 1.6090x over previous
//
#include <hip/hip_runtime.h>

// BoTNet attention, MI355X bf16-MFMA, round 16.
//  * raw .view: (b,o,s) row-major == (bh,i,d) row-major -> no relayout.
//  * pos bias folded into K; log2(e) folded into Q scale (exp2 softmax).
//  * S^T trick + pi-permuted K staging: softmaxed accumulators packed to bf16
//    ARE the PV A-fragments. pi: pr = (r&0x23)|((r&0x0C)<<1)|((r&0x10)>>2).
//  * R9: BK=128/buffer, ones-B MFMA row sums, setprio. flash 78->69us.
//  * R12: in-block KV-split (512 thr), in-LDS combine, f32 out. 170.7us.
//  * R14 (REVERTED): ds_read_b64_tr_b16 V path: absmax fail.
//  * R15 (REVERTED): reg-transpose V staging: 16-way ds_write bank conflict
//    (structural: d-major rows + wave carries only 8 j x 8 d-groups) +
//    vmcnt drain mid-pipeline -> flash 190us. v_transpose round-trip is
//    the cheaper price; fusion closed.
//  * R16: R12 pipeline verbatim + qkv tile 32->64 spatial cols/block
//    (grid 128->64 x4): halves the per-block W re-read L2 traffic
//    (196->98 MB), doubles MFMA work per Bs staging. Isolated change.
// ws: Q | K' | V | V^T (8 MiB each) | Wb16.

typedef float  f32x4  __attribute__((ext_vector_type(4)));
typedef __bf16 bf16x8 __attribute__((ext_vector_type(8)));
typedef __bf16 bf16x4 __attribute__((ext_vector_type(4)));

__device__ inline float fast_exp2(float x) {
#if __has_builtin(__builtin_amdgcn_exp2f)
  return __builtin_amdgcn_exp2f(x);
#else
  return exp2f(x);
#endif
}

__device__ inline void glds16(const __bf16* g, __bf16* l) {
  __builtin_amdgcn_global_load_lds(
      (const __attribute__((address_space(1))) void*)g,
      (__attribute__((address_space(3))) void*)l, 16, 0, 0);
}

// ---------------------------------------------------------------------------
// Kernel 0: W f32 -> bf16.
// ---------------------------------------------------------------------------
__global__ __launch_bounds__(256) void w_cvt(
    const float* __restrict__ w, __bf16* __restrict__ wb)
{
  int idx = blockIdx.x * 256 + threadIdx.x;
  f32x4 v = ((const f32x4*)w)[idx];
  bf16x4 o; o[0]=(__bf16)v[0]; o[1]=(__bf16)v[1]; o[2]=(__bf16)v[2]; o[3]=(__bf16)v[3];
  ((bf16x4*)wb)[idx] = o;
}

// ---------------------------------------------------------------------------
// Kernel 1: qkv projection v4: 64 spatial cols/block (was 32).
// grid (64, 4), block 256.
// ---------------------------------------------------------------------------
__global__ __launch_bounds__(256) void qkv_proj(
    const float* __restrict__ fmap, const __bf16* __restrict__ wb,
    const float* __restrict__ ph,   const float* __restrict__ pw,
    __bf16* __restrict__ Qw, __bf16* __restrict__ Kw, __bf16* __restrict__ Vw)
{
  constexpr int LS = 264;
  __shared__ __bf16 Bs[64 * LS];          // 64 spatial x 256 k (33.8 KiB)
  const int tid  = threadIdx.x;
  const int wv   = tid >> 6;
  const int lane = tid & 63;
  const int quad = lane >> 4, l15 = lane & 15;
  const int n0 = blockIdx.x * 64;
  const int b  = blockIdx.y;

  // stage fmap tile: 256 k x 64 spatial, bf16-converted.
#pragma unroll
  for (int i = 0; i < 4; ++i) {
    int id = tid + i * 256;                // 1024 ids
    int ng = id & 15;                      // 16 spatial groups x 4 cols
    int kg = id >> 4;                      // 64 channel groups x 4
    const float* base = fmap + ((size_t)b * 256 + 4 * kg) * 4096 + n0 + 4 * ng;
    f32x4 v0 = *(const f32x4*)(base);
    f32x4 v1 = *(const f32x4*)(base + 4096);
    f32x4 v2 = *(const f32x4*)(base + 8192);
    f32x4 v3 = *(const f32x4*)(base + 12288);
#pragma unroll
    for (int j = 0; j < 4; ++j) {
      bf16x4 o; o[0]=(__bf16)v0[j]; o[1]=(__bf16)v1[j]; o[2]=(__bf16)v2[j]; o[3]=(__bf16)v3[j];
      *(bf16x4*)(&Bs[(4 * ng + j) * LS + 4 * kg]) = o;
    }
  }
  __syncthreads();

  for (int mt = 0; mt < 12; ++mt) {
    const int region = mt >> 2;
    const int obase  = (mt & 3) * 64;
    const __bf16* aptr = wb + (size_t)(mt * 64 + 16 * wv + l15) * 256 + 8 * quad;

    f32x4 acc[4] = {};
#pragma unroll
    for (int k0 = 0; k0 < 256; k0 += 32) {
      bf16x8 af = *(const bf16x8*)(aptr + k0);
#pragma unroll
      for (int q = 0; q < 4; ++q) {
        bf16x8 bq = *(const bf16x8*)(&Bs[(16 * q + l15) * LS + k0 + 8 * quad]);
        acc[q] = __builtin_amdgcn_mfma_f32_16x16x32_bf16(af, bq, acc[q], 0, 0, 0);
      }
    }

#pragma unroll
    for (int t = 0; t < 4; ++t) {
#pragma unroll
      for (int rr = 0; rr < 4; ++rr) {
        int oreg = obase + 16 * wv + 4 * quad + rr;
        int s    = n0 + 16 * t + l15;
        float val = acc[t][rr];
        size_t off = ((size_t)(b * 256 + oreg)) * 4096 + s;
        if (region == 0) {
          Qw[off] = (__bf16)(val * 0.18033688f);      // 0.125 * log2(e)
        } else if (region == 1) {
          int g = oreg & 63;
          float bias = ph[g * 64 + (s & 63)] + pw[(s >> 6) * 64 + (s & 63)];
          Kw[off] = (__bf16)(val + bias);
        } else {
          Vw[off] = (__bf16)val;
        }
      }
    }
  }
}

// ---------------------------------------------------------------------------
// Kernel 2: V transpose per (b,h): (4096 j x 64 d) -> (64 d x 4096 j)
// ---------------------------------------------------------------------------
__global__ __launch_bounds__(256) void v_transpose(
    const __bf16* __restrict__ Vw, __bf16* __restrict__ Vt)
{
  __shared__ __bf16 T[64 * 72];
  const int tid = threadIdx.x;
  const int j0  = blockIdx.x * 64;
  const int bh  = blockIdx.y;
  const __bf16* src = Vw + (size_t)bh * 262144;
#pragma unroll
  for (int i = 0; i < 2; ++i) {
    int id = tid + i * 256;
    int r = id >> 3, c = (id & 7) * 8;
    *(bf16x8*)(&T[r * 72 + c]) = *(const bf16x8*)(src + (size_t)(j0 + r) * 64 + c);
  }
  __syncthreads();
#pragma unroll
  for (int i = 0; i < 2; ++i) {
    int id = tid + i * 256;
    int d = id >> 3, jc = (id & 7) * 8;
    bf16x8 o;
#pragma unroll
    for (int z = 0; z < 8; ++z) o[z] = T[(jc + z) * 72 + d];
    *(bf16x8*)(Vt + ((size_t)bh * 64 + d) * 4096 + j0 + jc) = o;
  }
}

// ---------------------------------------------------------------------------
// Kernel 3: flash attention v12 (proven 69.6us). 512 threads = 8 waves;
// waves 0-3 kv [0,2048), waves 4-7 kv [2048,4096), same 256 Q rows. m=4 per
// wave, BK=128 per LDS buffer, 2-stage DMA pipeline, in-LDS partial combine,
// direct f32 out. grid (16,16), block 512.
// ---------------------------------------------------------------------------
__global__ __launch_bounds__(512, 2) void flash_attn(
    const __bf16* __restrict__ Qg, const __bf16* __restrict__ Kg,
    const __bf16* __restrict__ Vtg, float* __restrict__ out)
{
  // 128 KiB: K tiles [z][buf][4096] then V tiles [z][buf][4096].
  __shared__ __align__(16) __bf16 SMEM[65536];
  __bf16* Ks = SMEM;                      // 32768 elems (64 KiB)
  __bf16* Vs = SMEM + 32768;              // 32768 elems (64 KiB)

  const int tid  = threadIdx.x;
  const int wv   = tid >> 6;
  const int lane = tid & 63;
  const int quad = lane >> 4, l15 = lane & 15;
  const int zi   = wv >> 2;               // kv half this wave computes
  const int wl   = wv & 3;                // q-slot within the half
  const int bh = blockIdx.y;
  const int iw = blockIdx.x * 256 + 64 * wl;
  const __bf16* Qb = Qg  + (size_t)bh * 262144;
  const __bf16* Kb = Kg  + (size_t)bh * 262144;
  const __bf16* Vb = Vtg + (size_t)bh * 262144;

  // Q B-frags in registers
  bf16x8 qf[4][2];
#pragma unroll
  for (int m = 0; m < 4; ++m)
#pragma unroll
    for (int c = 0; c < 2; ++c)
      qf[m][c] = *(const bf16x8*)(Qb + (size_t)(iw + 16 * m + l15) * 64 + 32 * c + 8 * quad);

  // DMA staging (all 512 threads stage BOTH kv halves).
  const int r0  = tid >> 3;
  const int kch = tid & 7;
  const int xc  = (kch ^ (r0 & 7)) * 8;
  const int prr = (r0 & 0x23) | ((r0 & 0x0C) << 1) | ((r0 & 0x10) >> 2);
  const __bf16* kp0 = Kb + (size_t)prr * 64 + xc;             // kv half 0
  const __bf16* kp1 = Kb + (size_t)(2048 + prr) * 64 + xc;    // kv half 1
  const __bf16* vp0 = Vb + (size_t)r0 * 4096 + xc;
  const __bf16* vp1 = Vb + (size_t)r0 * 4096 + 2048 + xc;

  f32x4 acco[4][4] = {};
  f32x4 lacc[4] = {};                     // row sums via ones-B MFMA
  const int swz = (l15 & 7);

  bf16x8 onesb;
#pragma unroll
  for (int r = 0; r < 8; ++r) onesb[r] = (__bf16)1.0f;

  // --- staging: per buffer, 8 glds16/thread fill K/V for both halves. ---
  auto dma_tile = [&](int buf) {
    __bf16* kd0 = &Ks[buf * 8192 + tid * 8];            // z=0
    __bf16* kd1 = &Ks[16384 + buf * 8192 + tid * 8];    // z=1
    __bf16* vd0 = &Vs[buf * 8192 + tid * 8];
    __bf16* vd1 = &Vs[16384 + buf * 8192 + tid * 8];
    glds16(kp0, kd0);         kp0 += 4096;   // sub0 (+64 K rows)
    glds16(kp0, kd0 + 4096);  kp0 += 4096;   // sub1
    glds16(kp1, kd1);         kp1 += 4096;
    glds16(kp1, kd1 + 4096);  kp1 += 4096;
    glds16(vp0, vd0);         vp0 += 64;     // sub0 (+64 V^T cols)
    glds16(vp0, vd0 + 4096);  vp0 += 64;     // sub1
    glds16(vp1, vd1);         vp1 += 64;
    glds16(vp1, vd1 + 4096);  vp1 += 64;
  };

  auto compute_tile = [&](int buf, int sub) {
    const __bf16* Kbuf = &Ks[zi * 16384 + buf * 8192 + sub * 4096];
    const __bf16* Vbuf = &Vs[zi * 16384 + buf * 8192 + sub * 4096];
    // S^T = mfma(K-slot rows, Q rows)
    f32x4 sacc[4][4] = {};
    __builtin_amdgcn_s_setprio(1);
#pragma unroll
    for (int c = 0; c < 2; ++c) {
#pragma unroll
      for (int t = 0; t < 4; ++t) {
        bf16x8 ak = *(const bf16x8*)(&Kbuf[(16 * t + l15) * 64 + (((4 * c + quad) ^ swz) * 8)]);
#pragma unroll
        for (int m = 0; m < 4; ++m)
          sacc[m][t] = __builtin_amdgcn_mfma_f32_16x16x32_bf16(ak, qf[m][c], sacc[m][t], 0, 0, 0);
      }
    }
    __builtin_amdgcn_s_setprio(0);
    // softmax numerator + pack PV A-frags (identity via pi)
    bf16x8 pf[4][2];
#pragma unroll
    for (int m = 0; m < 4; ++m) {
#pragma unroll
      for (int t = 0; t < 4; ++t)
#pragma unroll
        for (int r = 0; r < 4; ++r)
          sacc[m][t][r] = fast_exp2(sacc[m][t][r]);
#pragma unroll
      for (int c2 = 0; c2 < 2; ++c2) {
        bf16x8 a;
#pragma unroll
        for (int r = 0; r < 4; ++r) {
          a[r]     = (__bf16)sacc[m][2 * c2][r];
          a[4 + r] = (__bf16)sacc[m][2 * c2 + 1][r];
        }
        pf[m][c2] = a;
      }
    }
    // O += P . V ; l += P . 1 (ones-B MFMA row sums, all 16 cols identical)
    __builtin_amdgcn_s_setprio(1);
#pragma unroll
    for (int c2 = 0; c2 < 2; ++c2) {
#pragma unroll
      for (int t = 0; t < 4; ++t) {
        bf16x8 bv = *(const bf16x8*)(&Vbuf[(16 * t + l15) * 64 + (((4 * c2 + quad) ^ swz) * 8)]);
#pragma unroll
        for (int m = 0; m < 4; ++m)
          acco[m][t] = __builtin_amdgcn_mfma_f32_16x16x32_bf16(pf[m][c2], bv, acco[m][t], 0, 0, 0);
      }
#pragma unroll
      for (int m = 0; m < 4; ++m)
        lacc[m] = __builtin_amdgcn_mfma_f32_16x16x32_bf16(pf[m][c2], onesb, lacc[m], 0, 0, 0);
    }
    __builtin_amdgcn_s_setprio(0);
  };

  // --- 2-stage pipeline: 1 barrier per 128-row buffer (2 sub-tiles); DMA
  // issued a full compute phase before its vmcnt(0) drain at the next
  // barrier. 16 buffer fills cover each 2048-row kv half. ---
  dma_tile(0);
  for (int it = 0; it < 16; it += 2) {
    __syncthreads();                      // buf0 resident; buf1 reads done
    dma_tile(1);
    compute_tile(0, 0);
    compute_tile(0, 1);
    __syncthreads();                      // buf1 resident; buf0 reads done
    if (it < 14) dma_tile(0);
    compute_tile(1, 0);
    compute_tile(1, 1);
  }

  // --- epilogue: in-LDS partial combine, normalized f32 out. ---
  __syncthreads();                        // K/V tiles dead; reuse as f32 X
  float* X = (float*)SMEM;                // 256 slots x 84 f32 (86 KiB)
  const int slot = (wl * 64 + lane) * 84;
  if (zi == 1) {
#pragma unroll
    for (int m = 0; m < 4; ++m) {
#pragma unroll
      for (int t = 0; t < 4; ++t)
        *(f32x4*)(&X[slot + m * 16 + t * 4]) = acco[m][t];
      *(f32x4*)(&X[slot + 64 + m * 4]) = lacc[m];
    }
  }
  __syncthreads();
  if (zi == 0) {
    float* Ob = out + (size_t)bh * 262144;
#pragma unroll
    for (int m = 0; m < 4; ++m) {
      f32x4 l1 = *(const f32x4*)(&X[slot + 64 + m * 4]);
      f32x4 lt = lacc[m] + l1;
      f32x4 inv;
#pragma unroll
      for (int r = 0; r < 4; ++r) inv[r] = 1.0f / lt[r];
#pragma unroll
      for (int t = 0; t < 4; ++t) {
        f32x4 o1 = *(const f32x4*)(&X[slot + m * 16 + t * 4]);
        f32x4 ot = acco[m][t] + o1;
#pragma unroll
        for (int r = 0; r < 4; ++r)
          Ob[(size_t)(iw + 16 * m + 4 * quad + r) * 64 + 16 * t + l15] =
              ot[r] * inv[r];
      }
    }
  }
}

// ---------------------------------------------------------------------------
extern "C" void kernel_launch(void* const* d_in, const int* in_sizes, int n_in,
                              void* d_out, int out_size, void* d_ws, size_t ws_size,
                              hipStream_t stream) {
  const float* fmap = (const float*)d_in[0];
  const float* w    = (const float*)d_in[1];
  const float* ph   = (const float*)d_in[2];
  const float* pw   = (const float*)d_in[3];
  float* out = (float*)d_out;

  __bf16* Qw = (__bf16*)d_ws;            // 4*256*4096 elems each (8 MiB)
  __bf16* Kw = Qw + 4194304;
  __bf16* Vw = Kw + 4194304;
  __bf16* Vt = Vw + 4194304;
  __bf16* Wb16 = Vt + 4194304;           // 768*256 bf16 (384 KiB)

  w_cvt      <<<dim3(192),    256, 0, stream>>>(w, Wb16);
  qkv_proj   <<<dim3(64, 4),  256, 0, stream>>>(fmap, Wb16, ph, pw, Qw, Kw, Vw);
  v_transpose<<<dim3(64, 16), 256, 0, stream>>>(Vw, Vt);
  flash_attn <<<dim3(16, 16), 512, 0, stream>>>(Qw, Kw, Vt, out);
}

// Round 12
// 172.223 us; speedup vs baseline: 1.6191x; 1.0063x over previous
//
#include <hip/hip_runtime.h>

// BoTNet attention, MI355X bf16-MFMA, round 17.
//  * raw .view: (b,o,s) row-major == (bh,i,d) row-major -> no relayout.
//  * pos bias folded into K; log2(e) folded into Q scale (exp2 softmax).
//  * S^T trick + pi-permuted K staging: softmaxed accumulators packed to bf16
//    ARE the PV A-fragments. pi: pr = (r&0x23)|((r&0x0C)<<1)|((r&0x10)>>2).
//  * R9: BK=128/buffer, ones-B MFMA row sums, setprio. flash 78->69us.
//  * R12: in-block KV-split (512 thr), in-LDS combine, f32 out. 170.7us.
//  * R14/R15 (REVERTED): both V-transpose-fusion attempts failed.
//  * R16: qkv NB=64 null within +-8us total noise -> reverted to NB=32.
//  * R17: T1 XCD swizzle on flash. FETCH 69.7MB vs 24MB unique input =
//    cross-XCD K/V re-fetch (16 x-blocks of one bh spread over 8 L2s).
//    Bijective remap l=by*16+bx -> bh=2(l&7)+((l>>3)&1), x=l>>4: XCD k owns
//    bh {2k,2k+1} entirely -> K/V panels fetched ~once. Zero-risk remap.
// ws: Q | K' | V | V^T (8 MiB each) | Wb16.

typedef float  f32x4  __attribute__((ext_vector_type(4)));
typedef __bf16 bf16x8 __attribute__((ext_vector_type(8)));
typedef __bf16 bf16x4 __attribute__((ext_vector_type(4)));

__device__ inline float fast_exp2(float x) {
#if __has_builtin(__builtin_amdgcn_exp2f)
  return __builtin_amdgcn_exp2f(x);
#else
  return exp2f(x);
#endif
}

__device__ inline void glds16(const __bf16* g, __bf16* l) {
  __builtin_amdgcn_global_load_lds(
      (const __attribute__((address_space(1))) void*)g,
      (__attribute__((address_space(3))) void*)l, 16, 0, 0);
}

// ---------------------------------------------------------------------------
// Kernel 0: W f32 -> bf16.
// ---------------------------------------------------------------------------
__global__ __launch_bounds__(256) void w_cvt(
    const float* __restrict__ w, __bf16* __restrict__ wb)
{
  int idx = blockIdx.x * 256 + threadIdx.x;
  f32x4 v = ((const f32x4*)w)[idx];
  bf16x4 o; o[0]=(__bf16)v[0]; o[1]=(__bf16)v[1]; o[2]=(__bf16)v[2]; o[3]=(__bf16)v[3];
  ((bf16x4*)wb)[idx] = o;
}

// ---------------------------------------------------------------------------
// Kernel 1: qkv projection (R12 version, NB=32).
// ---------------------------------------------------------------------------
__global__ __launch_bounds__(256) void qkv_proj(
    const float* __restrict__ fmap, const __bf16* __restrict__ wb,
    const float* __restrict__ ph,   const float* __restrict__ pw,
    __bf16* __restrict__ Qw, __bf16* __restrict__ Kw, __bf16* __restrict__ Vw)
{
  constexpr int LS = 264;
  __shared__ __bf16 Bs[32 * LS];
  const int tid  = threadIdx.x;
  const int wv   = tid >> 6;
  const int lane = tid & 63;
  const int quad = lane >> 4, l15 = lane & 15;
  const int n0 = blockIdx.x * 32;
  const int b  = blockIdx.y;

#pragma unroll
  for (int i = 0; i < 2; ++i) {
    int id = tid + i * 256;
    int ng = id & 7;
    int kg = id >> 3;
    const float* base = fmap + ((size_t)b * 256 + 4 * kg) * 4096 + n0 + 4 * ng;
    f32x4 v0 = *(const f32x4*)(base);
    f32x4 v1 = *(const f32x4*)(base + 4096);
    f32x4 v2 = *(const f32x4*)(base + 8192);
    f32x4 v3 = *(const f32x4*)(base + 12288);
#pragma unroll
    for (int j = 0; j < 4; ++j) {
      bf16x4 o; o[0]=(__bf16)v0[j]; o[1]=(__bf16)v1[j]; o[2]=(__bf16)v2[j]; o[3]=(__bf16)v3[j];
      *(bf16x4*)(&Bs[(4 * ng + j) * LS + 4 * kg]) = o;
    }
  }
  __syncthreads();

  for (int mt = 0; mt < 12; ++mt) {
    const int region = mt >> 2;
    const int obase  = (mt & 3) * 64;
    const __bf16* aptr = wb + (size_t)(mt * 64 + 16 * wv + l15) * 256 + 8 * quad;

    f32x4 acc[2] = {};
#pragma unroll
    for (int k0 = 0; k0 < 256; k0 += 32) {
      bf16x8 af = *(const bf16x8*)(aptr + k0);
      bf16x8 b0 = *(const bf16x8*)(&Bs[(l15)      * LS + k0 + 8 * quad]);
      bf16x8 b1 = *(const bf16x8*)(&Bs[(16 + l15) * LS + k0 + 8 * quad]);
      acc[0] = __builtin_amdgcn_mfma_f32_16x16x32_bf16(af, b0, acc[0], 0, 0, 0);
      acc[1] = __builtin_amdgcn_mfma_f32_16x16x32_bf16(af, b1, acc[1], 0, 0, 0);
    }

#pragma unroll
    for (int t = 0; t < 2; ++t) {
#pragma unroll
      for (int rr = 0; rr < 4; ++rr) {
        int oreg = obase + 16 * wv + 4 * quad + rr;
        int s    = n0 + 16 * t + l15;
        float val = acc[t][rr];
        size_t off = ((size_t)(b * 256 + oreg)) * 4096 + s;
        if (region == 0) {
          Qw[off] = (__bf16)(val * 0.18033688f);      // 0.125 * log2(e)
        } else if (region == 1) {
          int g = oreg & 63;
          float bias = ph[g * 64 + (s & 63)] + pw[(s >> 6) * 64 + (s & 63)];
          Kw[off] = (__bf16)(val + bias);
        } else {
          Vw[off] = (__bf16)val;
        }
      }
    }
  }
}

// ---------------------------------------------------------------------------
// Kernel 2: V transpose per (b,h): (4096 j x 64 d) -> (64 d x 4096 j)
// ---------------------------------------------------------------------------
__global__ __launch_bounds__(256) void v_transpose(
    const __bf16* __restrict__ Vw, __bf16* __restrict__ Vt)
{
  __shared__ __bf16 T[64 * 72];
  const int tid = threadIdx.x;
  const int j0  = blockIdx.x * 64;
  const int bh  = blockIdx.y;
  const __bf16* src = Vw + (size_t)bh * 262144;
#pragma unroll
  for (int i = 0; i < 2; ++i) {
    int id = tid + i * 256;
    int r = id >> 3, c = (id & 7) * 8;
    *(bf16x8*)(&T[r * 72 + c]) = *(const bf16x8*)(src + (size_t)(j0 + r) * 64 + c);
  }
  __syncthreads();
#pragma unroll
  for (int i = 0; i < 2; ++i) {
    int id = tid + i * 256;
    int d = id >> 3, jc = (id & 7) * 8;
    bf16x8 o;
#pragma unroll
    for (int z = 0; z < 8; ++z) o[z] = T[(jc + z) * 72 + d];
    *(bf16x8*)(Vt + ((size_t)bh * 64 + d) * 4096 + j0 + jc) = o;
  }
}

// ---------------------------------------------------------------------------
// Kernel 3: flash attention v12 + XCD swizzle. 512 threads = 8 waves; waves
// 0-3 kv [0,2048), waves 4-7 kv [2048,4096), same 256 Q rows. m=4/wave,
// BK=128 per LDS buffer, 2-stage DMA pipeline, in-LDS partial combine,
// direct f32 out. grid (16,16), block 512.
// ---------------------------------------------------------------------------
__global__ __launch_bounds__(512, 2) void flash_attn(
    const __bf16* __restrict__ Qg, const __bf16* __restrict__ Kg,
    const __bf16* __restrict__ Vtg, float* __restrict__ out)
{
  // 128 KiB: K tiles [z][buf][4096] then V tiles [z][buf][4096].
  __shared__ __align__(16) __bf16 SMEM[65536];
  __bf16* Ks = SMEM;                      // 32768 elems (64 KiB)
  __bf16* Vs = SMEM + 32768;              // 32768 elems (64 KiB)

  const int tid  = threadIdx.x;
  const int wv   = tid >> 6;
  const int lane = tid & 63;
  const int quad = lane >> 4, l15 = lane & 15;
  const int zi   = wv >> 2;               // kv half this wave computes
  const int wl   = wv & 3;                // q-slot within the half
  // T1 XCD swizzle: dispatch id l round-robins XCDs (xcd ~ l&7). Give XCD k
  // both full bh panels {2k, 2k+1}: bh = 2(l&7)+((l>>3)&1), x = l>>4.
  // Bijection over l in [0,256).
  const int l   = blockIdx.y * 16 + blockIdx.x;
  const int bh  = 2 * (l & 7) + ((l >> 3) & 1);
  const int ibx = l >> 4;
  const int iw = ibx * 256 + 64 * wl;
  const __bf16* Qb = Qg  + (size_t)bh * 262144;
  const __bf16* Kb = Kg  + (size_t)bh * 262144;
  const __bf16* Vb = Vtg + (size_t)bh * 262144;

  // Q B-frags in registers
  bf16x8 qf[4][2];
#pragma unroll
  for (int m = 0; m < 4; ++m)
#pragma unroll
    for (int c = 0; c < 2; ++c)
      qf[m][c] = *(const bf16x8*)(Qb + (size_t)(iw + 16 * m + l15) * 64 + 32 * c + 8 * quad);

  // DMA staging (all 512 threads stage BOTH kv halves).
  const int r0  = tid >> 3;
  const int kch = tid & 7;
  const int xc  = (kch ^ (r0 & 7)) * 8;
  const int prr = (r0 & 0x23) | ((r0 & 0x0C) << 1) | ((r0 & 0x10) >> 2);
  const __bf16* kp0 = Kb + (size_t)prr * 64 + xc;             // kv half 0
  const __bf16* kp1 = Kb + (size_t)(2048 + prr) * 64 + xc;    // kv half 1
  const __bf16* vp0 = Vb + (size_t)r0 * 4096 + xc;
  const __bf16* vp1 = Vb + (size_t)r0 * 4096 + 2048 + xc;

  f32x4 acco[4][4] = {};
  f32x4 lacc[4] = {};                     // row sums via ones-B MFMA
  const int swz = (l15 & 7);

  bf16x8 onesb;
#pragma unroll
  for (int r = 0; r < 8; ++r) onesb[r] = (__bf16)1.0f;

  // --- staging: per buffer, 8 glds16/thread fill K/V for both halves. ---
  auto dma_tile = [&](int buf) {
    __bf16* kd0 = &Ks[buf * 8192 + tid * 8];            // z=0
    __bf16* kd1 = &Ks[16384 + buf * 8192 + tid * 8];    // z=1
    __bf16* vd0 = &Vs[buf * 8192 + tid * 8];
    __bf16* vd1 = &Vs[16384 + buf * 8192 + tid * 8];
    glds16(kp0, kd0);         kp0 += 4096;   // sub0 (+64 K rows)
    glds16(kp0, kd0 + 4096);  kp0 += 4096;   // sub1
    glds16(kp1, kd1);         kp1 += 4096;
    glds16(kp1, kd1 + 4096);  kp1 += 4096;
    glds16(vp0, vd0);         vp0 += 64;     // sub0 (+64 V^T cols)
    glds16(vp0, vd0 + 4096);  vp0 += 64;     // sub1
    glds16(vp1, vd1);         vp1 += 64;
    glds16(vp1, vd1 + 4096);  vp1 += 64;
  };

  auto compute_tile = [&](int buf, int sub) {
    const __bf16* Kbuf = &Ks[zi * 16384 + buf * 8192 + sub * 4096];
    const __bf16* Vbuf = &Vs[zi * 16384 + buf * 8192 + sub * 4096];
    // S^T = mfma(K-slot rows, Q rows)
    f32x4 sacc[4][4] = {};
    __builtin_amdgcn_s_setprio(1);
#pragma unroll
    for (int c = 0; c < 2; ++c) {
#pragma unroll
      for (int t = 0; t < 4; ++t) {
        bf16x8 ak = *(const bf16x8*)(&Kbuf[(16 * t + l15) * 64 + (((4 * c + quad) ^ swz) * 8)]);
#pragma unroll
        for (int m = 0; m < 4; ++m)
          sacc[m][t] = __builtin_amdgcn_mfma_f32_16x16x32_bf16(ak, qf[m][c], sacc[m][t], 0, 0, 0);
      }
    }
    __builtin_amdgcn_s_setprio(0);
    // softmax numerator + pack PV A-frags (identity via pi)
    bf16x8 pf[4][2];
#pragma unroll
    for (int m = 0; m < 4; ++m) {
#pragma unroll
      for (int t = 0; t < 4; ++t)
#pragma unroll
        for (int r = 0; r < 4; ++r)
          sacc[m][t][r] = fast_exp2(sacc[m][t][r]);
#pragma unroll
      for (int c2 = 0; c2 < 2; ++c2) {
        bf16x8 a;
#pragma unroll
        for (int r = 0; r < 4; ++r) {
          a[r]     = (__bf16)sacc[m][2 * c2][r];
          a[4 + r] = (__bf16)sacc[m][2 * c2 + 1][r];
        }
        pf[m][c2] = a;
      }
    }
    // O += P . V ; l += P . 1 (ones-B MFMA row sums, all 16 cols identical)
    __builtin_amdgcn_s_setprio(1);
#pragma unroll
    for (int c2 = 0; c2 < 2; ++c2) {
#pragma unroll
      for (int t = 0; t < 4; ++t) {
        bf16x8 bv = *(const bf16x8*)(&Vbuf[(16 * t + l15) * 64 + (((4 * c2 + quad) ^ swz) * 8)]);
#pragma unroll
        for (int m = 0; m < 4; ++m)
          acco[m][t] = __builtin_amdgcn_mfma_f32_16x16x32_bf16(pf[m][c2], bv, acco[m][t], 0, 0, 0);
      }
#pragma unroll
      for (int m = 0; m < 4; ++m)
        lacc[m] = __builtin_amdgcn_mfma_f32_16x16x32_bf16(pf[m][c2], onesb, lacc[m], 0, 0, 0);
    }
    __builtin_amdgcn_s_setprio(0);
  };

  // --- 2-stage pipeline: 1 barrier per 128-row buffer (2 sub-tiles); DMA
  // issued a full compute phase before its vmcnt(0) drain at the next
  // barrier. 16 buffer fills cover each 2048-row kv half. ---
  dma_tile(0);
  for (int it = 0; it < 16; it += 2) {
    __syncthreads();                      // buf0 resident; buf1 reads done
    dma_tile(1);
    compute_tile(0, 0);
    compute_tile(0, 1);
    __syncthreads();                      // buf1 resident; buf0 reads done
    if (it < 14) dma_tile(0);
    compute_tile(1, 0);
    compute_tile(1, 1);
  }

  // --- epilogue: in-LDS partial combine, normalized f32 out. ---
  __syncthreads();                        // K/V tiles dead; reuse as f32 X
  float* X = (float*)SMEM;                // 256 slots x 84 f32 (86 KiB)
  const int slot = (wl * 64 + lane) * 84;
  if (zi == 1) {
#pragma unroll
    for (int m = 0; m < 4; ++m) {
#pragma unroll
      for (int t = 0; t < 4; ++t)
        *(f32x4*)(&X[slot + m * 16 + t * 4]) = acco[m][t];
      *(f32x4*)(&X[slot + 64 + m * 4]) = lacc[m];
    }
  }
  __syncthreads();
  if (zi == 0) {
    float* Ob = out + (size_t)bh * 262144;
#pragma unroll
    for (int m = 0; m < 4; ++m) {
      f32x4 l1 = *(const f32x4*)(&X[slot + 64 + m * 4]);
      f32x4 lt = lacc[m] + l1;
      f32x4 inv;
#pragma unroll
      for (int r = 0; r < 4; ++r) inv[r] = 1.0f / lt[r];
#pragma unroll
      for (int t = 0; t < 4; ++t) {
        f32x4 o1 = *(const f32x4*)(&X[slot + m * 16 + t * 4]);
        f32x4 ot = acco[m][t] + o1;
#pragma unroll
        for (int r = 0; r < 4; ++r)
          Ob[(size_t)(iw + 16 * m + 4 * quad + r) * 64 + 16 * t + l15] =
              ot[r] * inv[r];
      }
    }
  }
}

// ---------------------------------------------------------------------------
extern "C" void kernel_launch(void* const* d_in, const int* in_sizes, int n_in,
                              void* d_out, int out_size, void* d_ws, size_t ws_size,
                              hipStream_t stream) {
  const float* fmap = (const float*)d_in[0];
  const float* w    = (const float*)d_in[1];
  const float* ph   = (const float*)d_in[2];
  const float* pw   = (const float*)d_in[3];
  float* out = (float*)d_out;

  __bf16* Qw = (__bf16*)d_ws;            // 4*256*4096 elems each (8 MiB)
  __bf16* Kw = Qw + 4194304;
  __bf16* Vw = Kw + 4194304;
  __bf16* Vt = Vw + 4194304;
  __bf16* Wb16 = (__bf16*)(Vt + 4194304);// 768*256 bf16 (384 KiB)

  w_cvt      <<<dim3(192),    256, 0, stream>>>(w, Wb16);
  qkv_proj   <<<dim3(128, 4), 256, 0, stream>>>(fmap, Wb16, ph, pw, Qw, Kw, Vw);
  v_transpose<<<dim3(64, 16), 256, 0, stream>>>(Vw, Vt);
  flash_attn <<<dim3(16, 16), 512, 0, stream>>>(Qw, Kw, Vt, out);
}